// Round 5
// baseline (101.518 us; speedup 1.0000x reference)
//
#include <hip/hip_runtime.h>
#include <hip/hip_bf16.h>

typedef __attribute__((ext_vector_type(4))) float f32x4;
typedef __attribute__((ext_vector_type(16))) float f32x16;
typedef __attribute__((ext_vector_type(8))) short bf16x8;

#define NH 8
#define HD 64
#define WSZ 128
#define DM 512
#define CHUNK 6
#define NTILE_TOTAL 3072

__device__ __forceinline__ unsigned int pk2bf(float lo, float hi) {
    union { __hip_bfloat162 h; unsigned int u; } r;
    r.h = __float22bfloat162_rn(make_float2(lo, hi));
    return r.u;
}

__device__ __forceinline__ bf16x8 pack8(f32x4 a, f32x4 b) {
    union { unsigned int u[4]; bf16x8 v; } r;
    r.u[0] = pk2bf(a[0], a[1]);
    r.u[1] = pk2bf(a[2], a[3]);
    r.u[2] = pk2bf(b[0], b[1]);
    r.u[3] = pk2bf(b[2], b[3]);
    return r.v;
}

// lgkm-only barrier: ds ops drained, but vmcnt stays live across the barrier
// so prefetched global loads keep flying through the compute phase.
__device__ __forceinline__ void lds_barrier() {
    asm volatile("s_waitcnt lgkmcnt(0)" ::: "memory");
    __builtin_amdgcn_s_barrier();
}

// Persistent: 512 blocks x CHUNK=6 window-heads. Per tile: 32x32x16 MFMA,
// swapped QK^T -> S^T (lane-local softmax), P via cvt_pk+permlane32_swap,
// K/V bf16 LDS tiles (32 KB), K/V/Q of tile j+1 reg-prefetched during compute of j.
__global__ __launch_bounds__(256, 2) void wattn_kernel(
    const float* __restrict__ q1, const float* __restrict__ k1,
    const float* __restrict__ v1, float* __restrict__ o1, int nw1,
    const float* __restrict__ q2, const float* __restrict__ k2,
    const float* __restrict__ v2, float* __restrict__ o2, int nw2,
    int nt1)
{
    // K tile bf16 [128][64], swizzled: idx = row*64 + (col ^ ((row&7)<<3))
    __shared__ __align__(16) unsigned short Kl[128 * 64];
    // V^T tile bf16 [64][128], swizzled: idx = d*128 + (k ^ (((d>>1)&7)<<3))
    __shared__ __align__(16) unsigned short Vt[64 * 128];

    const int t = threadIdx.x;
    const int lane = t & 63;
    const int wid = t >> 6;
    const int hi = lane >> 5;   // 0..1
    const int c = lane & 31;    // 0..31
    const int qbase = wid * 32;

    // ---- prefetch register file: 24 x f32x4 = 96 VGPR ----
    f32x4 ka[4], kb[4], va[4], vb[4], qa[4], qb[4];

    auto tile_ptrs = [&](int ti, const float*& Qp, const float*& Kp,
                         const float*& Vp, float*& Op) {
        const float *q, *k, *v; float* o; int nw; int widx = ti;
        if (widx < nt1) { q = q1; k = k1; v = v1; o = o1; nw = nw1; }
        else { widx -= nt1; q = q2; k = k2; v = v2; o = o2; nw = nw2; }
        const int h = widx & (NH - 1);
        const int w = (widx / NH) % nw;
        const int b = (widx / NH) / nw;
        const size_t row0 = ((size_t)b * nw + w) * WSZ;
        Qp = q + row0 * DM + h * HD;
        Kp = k + row0 * DM + h * HD;
        Vp = v + row0 * DM + h * HD;
        Op = o + row0 * DM + h * HD;
    };

    auto issue = [&](const float* Qp, const float* Kp, const float* Vp) {
#pragma unroll
        for (int i = 0; i < 4; ++i) {               // K: 8 rows/wave, coalesced
            int row = i * 32 + (t >> 3);
            const float* src = Kp + (size_t)row * DM + (t & 7) * 8;
            ka[i] = *reinterpret_cast<const f32x4*>(src);
            kb[i] = *reinterpret_cast<const f32x4*>(src + 4);
        }
#pragma unroll
        for (int i = 0; i < 4; ++i) {               // V: row-pairs, coalesced
            int rp = i * 16 + (t >> 4);
            int dc = (t & 15) * 4;
            va[i] = *reinterpret_cast<const f32x4*>(Vp + (size_t)(2 * rp) * DM + dc);
            vb[i] = *reinterpret_cast<const f32x4*>(Vp + (size_t)(2 * rp + 1) * DM + dc);
        }
#pragma unroll
        for (int ks = 0; ks < 4; ++ks) {            // Q: B-fragment direct
            const float* src = Qp + (size_t)(qbase + c) * DM + ks * 16 + hi * 8;
            qa[ks] = *reinterpret_cast<const f32x4*>(src);
            qb[ks] = *reinterpret_cast<const f32x4*>(src + 4);
        }
    };

    const int ti0 = blockIdx.x * CHUNK;
    const float *Qp, *Kp, *Vp; float* Op;
    tile_ptrs(ti0, Qp, Kp, Vp, Op);
    issue(Qp, Kp, Vp);

    for (int j = 0; j < CHUNK; ++j) {
        // ---- cvt staged regs -> LDS (vmcnt waits inserted per-reg by compiler) ----
#pragma unroll
        for (int i = 0; i < 4; ++i) {
            int row = i * 32 + (t >> 3);
            int colf = (t & 7) * 8;
            int base = row * 64, sw = (row & 7) << 3;
            *reinterpret_cast<unsigned int*>(&Kl[base + (colf ^ sw)]) = pk2bf(ka[i][0], ka[i][1]);
            *reinterpret_cast<unsigned int*>(&Kl[base + ((colf + 2) ^ sw)]) = pk2bf(ka[i][2], ka[i][3]);
            *reinterpret_cast<unsigned int*>(&Kl[base + ((colf + 4) ^ sw)]) = pk2bf(kb[i][0], kb[i][1]);
            *reinterpret_cast<unsigned int*>(&Kl[base + ((colf + 6) ^ sw)]) = pk2bf(kb[i][2], kb[i][3]);
        }
#pragma unroll
        for (int i = 0; i < 4; ++i) {
            int rp = i * 16 + (t >> 4);
            int dc = (t & 15) * 4;
#pragma unroll
            for (int jj = 0; jj < 4; ++jj) {
                int d = dc + jj;
                *reinterpret_cast<unsigned int*>(
                    &Vt[d * 128 + ((2 * rp) ^ (((d >> 1) & 7) << 3))]) = pk2bf(va[i][jj], vb[i][jj]);
            }
        }
        bf16x8 qf[4];
#pragma unroll
        for (int ks = 0; ks < 4; ++ks) qf[ks] = pack8(qa[ks], qb[ks]);

        lds_barrier();                 // LDS tiles ready; vmcnt NOT drained

        // ---- issue next tile's loads; they fly during the compute below ----
        float* OpStore = Op;
        if (j + 1 < CHUNK) {
            tile_ptrs(ti0 + j + 1, Qp, Kp, Vp, Op);
            issue(Qp, Kp, Vp);
        }

        // ---- S^T = K Q^T : D col=c (q), row k = mf*32+(reg&3)+8*(reg>>2)+4*hi ----
        f32x16 acc[4] = {};
#pragma unroll
        for (int ks = 0; ks < 4; ++ks) {
#pragma unroll
            for (int mf = 0; mf < 4; ++mf) {
                const bf16x8 kf = *reinterpret_cast<const bf16x8*>(
                    &Kl[(mf * 32 + c) * 64 + ((ks * 16 + hi * 8) ^ ((c & 7) << 3))]);
                acc[mf] = __builtin_amdgcn_mfma_f32_32x32x16_bf16(kf, qf[ks], acc[mf], 0, 0, 0);
            }
        }

        // ---- softmax over k: lane-local, tree-reduced, one cross-half shfl ----
        const float CEXP = 0.125f * 1.4426950408889634f;
        float mxa = fmaxf(acc[0][0], acc[1][0]);
        float mxb = fmaxf(acc[2][0], acc[3][0]);
#pragma unroll
        for (int e = 1; e < 16; ++e) {
            mxa = fmaxf(mxa, fmaxf(acc[0][e], acc[1][e]));
            mxb = fmaxf(mxb, fmaxf(acc[2][e], acc[3][e]));
        }
        float mx = fmaxf(mxa, mxb);
        mx = fmaxf(mx, __shfl_xor(mx, 32));
        const float mxc = mx * CEXP;
        float s0 = 0.f, s1 = 0.f, s2 = 0.f, s3 = 0.f;
#pragma unroll
        for (int e = 0; e < 16; ++e) {
            float p0 = exp2f(acc[0][e] * CEXP - mxc);
            float p1 = exp2f(acc[1][e] * CEXP - mxc);
            float p2 = exp2f(acc[2][e] * CEXP - mxc);
            float p3 = exp2f(acc[3][e] * CEXP - mxc);
            acc[0][e] = p0; acc[1][e] = p1; acc[2][e] = p2; acc[3][e] = p3;
            s0 += p0; s1 += p1; s2 += p2; s3 += p3;
        }
        float sum = (s0 + s1) + (s2 + s3);
        sum += __shfl_xor(sum, 32);
        const float rinv = 1.0f / sum;

        // ---- O = P V : pack P + permlane32_swap -> A-frag in regs ----
        f32x16 oacc[2] = {};
#pragma unroll
        for (int f = 0; f < 4; ++f) {
#pragma unroll
            for (int p = 0; p < 2; ++p) {
                const int kb2 = f * 2 + p;
                unsigned int U0 = pk2bf(acc[f][8 * p + 0], acc[f][8 * p + 1]);
                unsigned int U1 = pk2bf(acc[f][8 * p + 2], acc[f][8 * p + 3]);
                unsigned int U2 = pk2bf(acc[f][8 * p + 4], acc[f][8 * p + 5]);
                unsigned int U3 = pk2bf(acc[f][8 * p + 6], acc[f][8 * p + 7]);
                asm volatile("v_permlane32_swap_b32 %0, %1" : "+v"(U0), "+v"(U2));
                asm volatile("v_permlane32_swap_b32 %0, %1" : "+v"(U1), "+v"(U3));
                union { unsigned int u[4]; bf16x8 v; } A;
                A.u[0] = U0; A.u[1] = U1; A.u[2] = U2; A.u[3] = U3;
#pragma unroll
                for (int nf = 0; nf < 2; ++nf) {
                    const int d = nf * 32 + c;
                    const bf16x8 vf = *reinterpret_cast<const bf16x8*>(
                        &Vt[d * 128 + ((kb2 * 16 + hi * 8) ^ (((d >> 1) & 7) << 3))]);
                    oacc[nf] = __builtin_amdgcn_mfma_f32_32x32x16_bf16(A.v, vf, oacc[nf], 0, 0, 0);
                }
            }
        }

        // ---- store O with deferred 1/rowsum broadcast ----
#pragma unroll
        for (int reg = 0; reg < 16; ++reg) {
            const int qr = (reg & 3) + 8 * (reg >> 2) + 4 * hi;
            const float rv = __shfl(rinv, qr);
#pragma unroll
            for (int nf = 0; nf < 2; ++nf) {
                OpStore[(size_t)(qbase + qr) * DM + nf * 32 + c] = oacc[nf][reg] * rv;
            }
        }

        lds_barrier();                 // readers done before next iter's LDS writes
    }
}

extern "C" void kernel_launch(void* const* d_in, const int* in_sizes, int n_in,
                              void* d_out, int out_size, void* d_ws, size_t ws_size,
                              hipStream_t stream) {
    const float* q1 = (const float*)d_in[0];
    const float* k1 = (const float*)d_in[1];
    const float* v1 = (const float*)d_in[2];
    const float* q2 = (const float*)d_in[3];
    const float* k2 = (const float*)d_in[4];
    const float* v2 = (const float*)d_in[5];

    const int B = 8;
    const int nw1 = in_sizes[0] / (B * DM * WSZ);   // 32
    const int nw2 = in_sizes[3] / (B * DM * WSZ);   // 16

    float* o1 = (float*)d_out;
    float* o2 = o1 + (size_t)in_sizes[0];

    const int nt1 = B * nw1 * NH;                   // 2048 tiles (set 1)
    const int nt2 = B * nw2 * NH;                   // 1024 tiles (set 2)
    const int nblk = (nt1 + nt2) / CHUNK;           // 512 blocks x 6 tiles

    wattn_kernel<<<dim3(nblk), dim3(256), 0, stream>>>(
        q1, k1, v1, o1, nw1, q2, k2, v2, o2, nw2, nt1);
}

// Round 6
// 90.538 us; speedup vs baseline: 1.1213x; 1.1213x over previous
//
#include <hip/hip_runtime.h>
#include <hip/hip_bf16.h>

typedef __attribute__((ext_vector_type(4))) float f32x4;
typedef __attribute__((ext_vector_type(16))) float f32x16;
typedef __attribute__((ext_vector_type(8))) short bf16x8;

#define NH 8
#define HD 64
#define WSZ 128
#define DM 512

__device__ __forceinline__ unsigned int pk2bf(float lo, float hi) {
    union { __hip_bfloat162 h; unsigned int u; } r;
    r.h = __float22bfloat162_rn(make_float2(lo, hi));
    return r.u;
}

__device__ __forceinline__ bf16x8 pack8(f32x4 a, f32x4 b) {
    union { unsigned int u[4]; bf16x8 v; } r;
    r.u[0] = pk2bf(a[0], a[1]);
    r.u[1] = pk2bf(a[2], a[3]);
    r.u[2] = pk2bf(b[0], b[1]);
    r.u[3] = pk2bf(b[2], b[3]);
    return r.v;
}

// One block = one (batch, window, head). 4 waves, each owns 32 q-columns of S^T.
// 32x32x16 MFMA; swapped QK^T -> S^T so softmax is lane-local and P->PV goes
// through cvt_pk + v_permlane32_swap (no LDS for P). LDS: K 16K + Vt 16K = 32K.
// XCD swizzle: all 8 heads of a window land on the SAME XCD, concurrently,
// so the window's 768 KB of Q/K/V fp32 rows are read into that XCD's L2 once.
__global__ __launch_bounds__(256, 4) void wattn_kernel(
    const float* __restrict__ q1, const float* __restrict__ k1,
    const float* __restrict__ v1, float* __restrict__ o1, int nw1,
    const float* __restrict__ q2, const float* __restrict__ k2,
    const float* __restrict__ v2, float* __restrict__ o2, int nw2,
    int nblk1, int cpx)
{
    // K tile bf16 [128][64], swizzled: idx = row*64 + (col ^ ((row&7)<<3))
    __shared__ __align__(16) unsigned short Kl[128 * 64];
    // V^T tile bf16 [64][128], swizzled: idx = d*128 + (k ^ (((d>>1)&7)<<3))
    __shared__ __align__(16) unsigned short Vt[64 * 128];

    const int t = threadIdx.x;
    const int lane = t & 63;
    const int wid = t >> 6;
    const int hi = lane >> 5;   // 0..1
    const int c = lane & 31;    // 0..31

    // ---- XCD-aware remap: hardware assigns blockIdx round-robin to XCDs; ----
    // ---- give XCD x the contiguous tile range [x*cpx, (x+1)*cpx).         ----
    int bid = (blockIdx.x & 7) * cpx + (blockIdx.x >> 3);

    const float *q, *k, *v; float* o; int nw;
    if (bid < nblk1) { q = q1; k = k1; v = v1; o = o1; nw = nw1; }
    else { bid -= nblk1; q = q2; k = k2; v = v2; o = o2; nw = nw2; }

    const int h = bid & (NH - 1);
    const int w = (bid / NH) % nw;
    const int b = (bid / NH) / nw;

    const size_t row0 = ((size_t)b * nw + w) * WSZ;
    const float* Qp = q + row0 * DM + h * HD;
    const float* Kp = k + row0 * DM + h * HD;
    const float* Vp = v + row0 * DM + h * HD;
    float* Op = o + row0 * DM + h * HD;

    // ---- stage K: coalesced, conflict-free b128 writes ----
#pragma unroll
    for (int i = 0; i < 4; ++i) {
        int row = i * 32 + (t >> 3);
        int colf = (t & 7) * 8;
        const float* src = Kp + (size_t)row * DM + colf;
        f32x4 a = *reinterpret_cast<const f32x4*>(src);
        f32x4 bq = *reinterpret_cast<const f32x4*>(src + 4);
        int base = row * 64, sw = (row & 7) << 3;
        *reinterpret_cast<unsigned int*>(&Kl[base + (colf ^ sw)]) = pk2bf(a[0], a[1]);
        *reinterpret_cast<unsigned int*>(&Kl[base + ((colf + 2) ^ sw)]) = pk2bf(a[2], a[3]);
        *reinterpret_cast<unsigned int*>(&Kl[base + ((colf + 4) ^ sw)]) = pk2bf(bq[0], bq[1]);
        *reinterpret_cast<unsigned int*>(&Kl[base + ((colf + 6) ^ sw)]) = pk2bf(bq[2], bq[3]);
    }

    // ---- stage V transposed: paired-k b32 writes ----
#pragma unroll
    for (int i = 0; i < 4; ++i) {
        int rp = i * 16 + (t >> 4);          // row-pair: rows 2rp, 2rp+1
        int dc = (t & 15) * 4;
        f32x4 va = *reinterpret_cast<const f32x4*>(Vp + (size_t)(2 * rp) * DM + dc);
        f32x4 vb = *reinterpret_cast<const f32x4*>(Vp + (size_t)(2 * rp + 1) * DM + dc);
#pragma unroll
        for (int j = 0; j < 4; ++j) {
            int d = dc + j;
            int idx = d * 128 + ((2 * rp) ^ (((d >> 1) & 7) << 3));   // even
            *reinterpret_cast<unsigned int*>(&Vt[idx]) = pk2bf(va[j], vb[j]);
        }
    }

    // ---- Q fragments direct from global (B-operand: q=qbase+c, d=ks*16+hi*8+j) ----
    const int qbase = wid * 32;
    bf16x8 qf[4];
#pragma unroll
    for (int ks = 0; ks < 4; ++ks) {
        const float* src = Qp + (size_t)(qbase + c) * DM + ks * 16 + hi * 8;
        f32x4 a = *reinterpret_cast<const f32x4*>(src);
        f32x4 bq = *reinterpret_cast<const f32x4*>(src + 4);
        qf[ks] = pack8(a, bq);
    }

    __syncthreads();

    // ---- S^T = K Q^T : acc[mf], D: col=c (q), row k = mf*32+(reg&3)+8*(reg>>2)+4*hi
    f32x16 acc[4] = {};
#pragma unroll
    for (int ks = 0; ks < 4; ++ks) {
#pragma unroll
        for (int mf = 0; mf < 4; ++mf) {
            const bf16x8 kf = *reinterpret_cast<const bf16x8*>(
                &Kl[(mf * 32 + c) * 64 + ((ks * 16 + hi * 8) ^ ((c & 7) << 3))]);
            acc[mf] = __builtin_amdgcn_mfma_f32_32x32x16_bf16(kf, qf[ks], acc[mf], 0, 0, 0);
        }
    }

    // ---- softmax over k: 64 lane-local + 1 cross-half reduce ----
    const float CEXP = 0.125f * 1.4426950408889634f;
    float mxa = fmaxf(acc[0][0], acc[1][0]);
    float mxb = fmaxf(acc[2][0], acc[3][0]);
#pragma unroll
    for (int e = 1; e < 16; ++e) {
        mxa = fmaxf(mxa, fmaxf(acc[0][e], acc[1][e]));
        mxb = fmaxf(mxb, fmaxf(acc[2][e], acc[3][e]));
    }
    float mx = fmaxf(mxa, mxb);
    mx = fmaxf(mx, __shfl_xor(mx, 32));
    const float mxc = mx * CEXP;
    float s0 = 0.f, s1 = 0.f, s2 = 0.f, s3 = 0.f;
#pragma unroll
    for (int e = 0; e < 16; ++e) {
        float p0 = exp2f(acc[0][e] * CEXP - mxc);
        float p1 = exp2f(acc[1][e] * CEXP - mxc);
        float p2 = exp2f(acc[2][e] * CEXP - mxc);
        float p3 = exp2f(acc[3][e] * CEXP - mxc);
        acc[0][e] = p0; acc[1][e] = p1; acc[2][e] = p2; acc[3][e] = p3;
        s0 += p0; s1 += p1; s2 += p2; s3 += p3;
    }
    float sum = (s0 + s1) + (s2 + s3);
    sum += __shfl_xor(sum, 32);
    const float rinv = 1.0f / sum;

    // ---- O = P V : per 16-k block, pack P + permlane32_swap -> A-frag in regs ----
    f32x16 oacc[2] = {};
#pragma unroll
    for (int f = 0; f < 4; ++f) {
#pragma unroll
        for (int p = 0; p < 2; ++p) {
            const int kb = f * 2 + p;
            unsigned int U0 = pk2bf(acc[f][8 * p + 0], acc[f][8 * p + 1]);
            unsigned int U1 = pk2bf(acc[f][8 * p + 2], acc[f][8 * p + 3]);
            unsigned int U2 = pk2bf(acc[f][8 * p + 4], acc[f][8 * p + 5]);
            unsigned int U3 = pk2bf(acc[f][8 * p + 6], acc[f][8 * p + 7]);
            // swap upper lanes of U0 with lower lanes of U2 (and U1<->U3):
            asm volatile("v_permlane32_swap_b32 %0, %1" : "+v"(U0), "+v"(U2));
            asm volatile("v_permlane32_swap_b32 %0, %1" : "+v"(U1), "+v"(U3));
            union { unsigned int u[4]; bf16x8 v; } A;
            A.u[0] = U0; A.u[1] = U1; A.u[2] = U2; A.u[3] = U3;
#pragma unroll
            for (int nf = 0; nf < 2; ++nf) {
                const int d = nf * 32 + c;
                const bf16x8 vf = *reinterpret_cast<const bf16x8*>(
                    &Vt[d * 128 + ((kb * 16 + hi * 8) ^ (((d >> 1) & 7) << 3))]);
                oacc[nf] = __builtin_amdgcn_mfma_f32_32x32x16_bf16(A.v, vf, oacc[nf], 0, 0, 0);
            }
        }
    }

    // ---- store O with deferred 1/rowsum broadcast from q-owner lanes ----
#pragma unroll
    for (int reg = 0; reg < 16; ++reg) {
        const int qr = (reg & 3) + 8 * (reg >> 2) + 4 * hi;
        const float rv = __shfl(rinv, qr);   // rinv for q-col qr lives at lane qr
#pragma unroll
        for (int nf = 0; nf < 2; ++nf) {
            Op[(size_t)(qbase + qr) * DM + nf * 32 + c] = oacc[nf][reg] * rv;
        }
    }
}

extern "C" void kernel_launch(void* const* d_in, const int* in_sizes, int n_in,
                              void* d_out, int out_size, void* d_ws, size_t ws_size,
                              hipStream_t stream) {
    const float* q1 = (const float*)d_in[0];
    const float* k1 = (const float*)d_in[1];
    const float* v1 = (const float*)d_in[2];
    const float* q2 = (const float*)d_in[3];
    const float* k2 = (const float*)d_in[4];
    const float* v2 = (const float*)d_in[5];

    const int B = 8;
    const int nw1 = in_sizes[0] / (B * DM * WSZ);   // 32
    const int nw2 = in_sizes[3] / (B * DM * WSZ);   // 16

    float* o1 = (float*)d_out;
    float* o2 = o1 + (size_t)in_sizes[0];

    const int nblk1 = B * nw1 * NH;                 // 2048
    const int nblk2 = B * nw2 * NH;                 // 1024
    const int ntot = nblk1 + nblk2;                 // 3072 (divisible by 8)
    const int cpx = ntot / 8;                       // 384 tiles per XCD

    wattn_kernel<<<dim3(ntot), dim3(256), 0, stream>>>(
        q1, k1, v1, o1, nw1, q2, k2, v2, o2, nw2, nblk1, cpx);
}

// Round 7
// 86.065 us; speedup vs baseline: 1.1795x; 1.0520x over previous
//
#include <hip/hip_runtime.h>
#include <hip/hip_bf16.h>

typedef __attribute__((ext_vector_type(4))) float f32x4;
typedef __attribute__((ext_vector_type(16))) float f32x16;
typedef __attribute__((ext_vector_type(8))) short bf16x8;

#define NH 8
#define HD 64
#define WSZ 128
#define DM 512

__device__ __forceinline__ unsigned int pk2bf(float lo, float hi) {
    union { __hip_bfloat162 h; unsigned int u; } r;
    r.h = __float22bfloat162_rn(make_float2(lo, hi));
    return r.u;
}

// One block = one (batch, window, head). 4 waves, each owns 32 q-columns of S^T.
// 32x32x16 MFMA; swapped QK^T -> S^T (lane-local softmax); P via
// cvt_pk + v_permlane32_swap (no LDS for P). LDS: K 16K + Vt 16K = 32K.
// KEY CHANGE vs r4: ALL 24 global loads issued back-to-back into registers
// (one vmcnt latency exposure per tile), conversions strictly after.
__global__ __launch_bounds__(256, 3) void wattn_kernel(
    const float* __restrict__ q1, const float* __restrict__ k1,
    const float* __restrict__ v1, float* __restrict__ o1, int nw1,
    const float* __restrict__ q2, const float* __restrict__ k2,
    const float* __restrict__ v2, float* __restrict__ o2, int nw2,
    int nblk1)
{
    // K tile bf16 [128][64], swizzled: idx = row*64 + (col ^ ((row&7)<<3))
    __shared__ __align__(16) unsigned short Kl[128 * 64];
    // V^T tile bf16 [64][128], swizzled: idx = d*128 + (k ^ (((d>>1)&7)<<3))
    __shared__ __align__(16) unsigned short Vt[64 * 128];

    const int t = threadIdx.x;
    const int lane = t & 63;
    const int wid = t >> 6;
    const int hi = lane >> 5;   // 0..1
    const int c = lane & 31;    // 0..31

    int bid = blockIdx.x;
    const float *q, *k, *v; float* o; int nw;
    if (bid < nblk1) { q = q1; k = k1; v = v1; o = o1; nw = nw1; }
    else { bid -= nblk1; q = q2; k = k2; v = v2; o = o2; nw = nw2; }

    const int h = bid & (NH - 1);
    const int w = (bid / NH) % nw;
    const int b = (bid / NH) / nw;

    const size_t row0 = ((size_t)b * nw + w) * WSZ;
    const float* Qp = q + row0 * DM + h * HD;
    const float* Kp = k + row0 * DM + h * HD;
    const float* Vp = v + row0 * DM + h * HD;
    float* Op = o + row0 * DM + h * HD;

    const int qbase = wid * 32;

    // ================= PHASE 1: issue ALL loads, zero uses =================
    f32x4 ka[4], kb[4], va[4], vb[4], qa[4], qb[4];
#pragma unroll
    for (int i = 0; i < 4; ++i) {               // K: coalesced rows
        const float* src = Kp + (size_t)(i * 32 + (t >> 3)) * DM + (t & 7) * 8;
        ka[i] = *reinterpret_cast<const f32x4*>(src);
        kb[i] = *reinterpret_cast<const f32x4*>(src + 4);
    }
#pragma unroll
    for (int i = 0; i < 4; ++i) {               // V: row-pairs
        int rp = i * 16 + (t >> 4);
        int dc = (t & 15) * 4;
        va[i] = *reinterpret_cast<const f32x4*>(Vp + (size_t)(2 * rp) * DM + dc);
        vb[i] = *reinterpret_cast<const f32x4*>(Vp + (size_t)(2 * rp + 1) * DM + dc);
    }
#pragma unroll
    for (int ks = 0; ks < 4; ++ks) {            // Q: B-fragment rows
        const float* src = Qp + (size_t)(qbase + c) * DM + ks * 16 + hi * 8;
        qa[ks] = *reinterpret_cast<const f32x4*>(src);
        qb[ks] = *reinterpret_cast<const f32x4*>(src + 4);
    }
    // Pin: no convert/LDS op may be hoisted above this point, so the 24
    // loads issue back-to-back and share ONE latency window.
    __builtin_amdgcn_sched_barrier(0);

    // ================= PHASE 2: convert + stage =================
#pragma unroll
    for (int i = 0; i < 4; ++i) {
        int row = i * 32 + (t >> 3);
        int colf = (t & 7) * 8;
        int base = row * 64, sw = (row & 7) << 3;
        *reinterpret_cast<unsigned int*>(&Kl[base + (colf ^ sw)]) = pk2bf(ka[i][0], ka[i][1]);
        *reinterpret_cast<unsigned int*>(&Kl[base + ((colf + 2) ^ sw)]) = pk2bf(ka[i][2], ka[i][3]);
        *reinterpret_cast<unsigned int*>(&Kl[base + ((colf + 4) ^ sw)]) = pk2bf(kb[i][0], kb[i][1]);
        *reinterpret_cast<unsigned int*>(&Kl[base + ((colf + 6) ^ sw)]) = pk2bf(kb[i][2], kb[i][3]);
    }
#pragma unroll
    for (int i = 0; i < 4; ++i) {
        int rp = i * 16 + (t >> 4);
        int dc = (t & 15) * 4;
#pragma unroll
        for (int j = 0; j < 4; ++j) {
            int d = dc + j;
            *reinterpret_cast<unsigned int*>(
                &Vt[d * 128 + ((2 * rp) ^ (((d >> 1) & 7) << 3))]) = pk2bf(va[i][j], vb[i][j]);
        }
    }
    bf16x8 qf[4];
#pragma unroll
    for (int ks = 0; ks < 4; ++ks) {
        union { unsigned int u[4]; bf16x8 v; } r;
        r.u[0] = pk2bf(qa[ks][0], qa[ks][1]);
        r.u[1] = pk2bf(qa[ks][2], qa[ks][3]);
        r.u[2] = pk2bf(qb[ks][0], qb[ks][1]);
        r.u[3] = pk2bf(qb[ks][2], qb[ks][3]);
        qf[ks] = r.v;
    }

    __syncthreads();

    // ---- S^T = K Q^T : acc[mf], D: col=c (q), row k = mf*32+(reg&3)+8*(reg>>2)+4*hi
    f32x16 acc[4] = {};
#pragma unroll
    for (int ks = 0; ks < 4; ++ks) {
#pragma unroll
        for (int mf = 0; mf < 4; ++mf) {
            const bf16x8 kf = *reinterpret_cast<const bf16x8*>(
                &Kl[(mf * 32 + c) * 64 + ((ks * 16 + hi * 8) ^ ((c & 7) << 3))]);
            acc[mf] = __builtin_amdgcn_mfma_f32_32x32x16_bf16(kf, qf[ks], acc[mf], 0, 0, 0);
        }
    }

    // ---- softmax over k: lane-local, tree-reduced, one cross-half shfl ----
    const float CEXP = 0.125f * 1.4426950408889634f;
    float mxa = fmaxf(acc[0][0], acc[1][0]);
    float mxb = fmaxf(acc[2][0], acc[3][0]);
#pragma unroll
    for (int e = 1; e < 16; ++e) {
        mxa = fmaxf(mxa, fmaxf(acc[0][e], acc[1][e]));
        mxb = fmaxf(mxb, fmaxf(acc[2][e], acc[3][e]));
    }
    float mx = fmaxf(mxa, mxb);
    mx = fmaxf(mx, __shfl_xor(mx, 32));
    const float mxc = mx * CEXP;
    float s0 = 0.f, s1 = 0.f, s2 = 0.f, s3 = 0.f;
#pragma unroll
    for (int e = 0; e < 16; ++e) {
        float p0 = exp2f(acc[0][e] * CEXP - mxc);
        float p1 = exp2f(acc[1][e] * CEXP - mxc);
        float p2 = exp2f(acc[2][e] * CEXP - mxc);
        float p3 = exp2f(acc[3][e] * CEXP - mxc);
        acc[0][e] = p0; acc[1][e] = p1; acc[2][e] = p2; acc[3][e] = p3;
        s0 += p0; s1 += p1; s2 += p2; s3 += p3;
    }
    float sum = (s0 + s1) + (s2 + s3);
    sum += __shfl_xor(sum, 32);
    const float rinv = 1.0f / sum;

    // ---- O = P V : per 16-k block, pack P + permlane32_swap -> A-frag in regs ----
    f32x16 oacc[2] = {};
#pragma unroll
    for (int f = 0; f < 4; ++f) {
#pragma unroll
        for (int p = 0; p < 2; ++p) {
            const int kb2 = f * 2 + p;
            unsigned int U0 = pk2bf(acc[f][8 * p + 0], acc[f][8 * p + 1]);
            unsigned int U1 = pk2bf(acc[f][8 * p + 2], acc[f][8 * p + 3]);
            unsigned int U2 = pk2bf(acc[f][8 * p + 4], acc[f][8 * p + 5]);
            unsigned int U3 = pk2bf(acc[f][8 * p + 6], acc[f][8 * p + 7]);
            asm volatile("v_permlane32_swap_b32 %0, %1" : "+v"(U0), "+v"(U2));
            asm volatile("v_permlane32_swap_b32 %0, %1" : "+v"(U1), "+v"(U3));
            union { unsigned int u[4]; bf16x8 v; } A;
            A.u[0] = U0; A.u[1] = U1; A.u[2] = U2; A.u[3] = U3;
#pragma unroll
            for (int nf = 0; nf < 2; ++nf) {
                const int d = nf * 32 + c;
                const bf16x8 vf = *reinterpret_cast<const bf16x8*>(
                    &Vt[d * 128 + ((kb2 * 16 + hi * 8) ^ (((d >> 1) & 7) << 3))]);
                oacc[nf] = __builtin_amdgcn_mfma_f32_32x32x16_bf16(A.v, vf, oacc[nf], 0, 0, 0);
            }
        }
    }

    // ---- store O with deferred 1/rowsum broadcast from q-owner lanes ----
#pragma unroll
    for (int reg = 0; reg < 16; ++reg) {
        const int qr = (reg & 3) + 8 * (reg >> 2) + 4 * hi;
        const float rv = __shfl(rinv, qr);
#pragma unroll
        for (int nf = 0; nf < 2; ++nf) {
            Op[(size_t)(qbase + qr) * DM + nf * 32 + c] = oacc[nf][reg] * rv;
        }
    }
}

extern "C" void kernel_launch(void* const* d_in, const int* in_sizes, int n_in,
                              void* d_out, int out_size, void* d_ws, size_t ws_size,
                              hipStream_t stream) {
    const float* q1 = (const float*)d_in[0];
    const float* k1 = (const float*)d_in[1];
    const float* v1 = (const float*)d_in[2];
    const float* q2 = (const float*)d_in[3];
    const float* k2 = (const float*)d_in[4];
    const float* v2 = (const float*)d_in[5];

    const int B = 8;
    const int nw1 = in_sizes[0] / (B * DM * WSZ);   // 32
    const int nw2 = in_sizes[3] / (B * DM * WSZ);   // 16

    float* o1 = (float*)d_out;
    float* o2 = o1 + (size_t)in_sizes[0];

    const int nblk1 = B * nw1 * NH;                 // 2048
    const int nblk2 = B * nw2 * NH;                 // 1024

    wattn_kernel<<<dim3(nblk1 + nblk2), dim3(256), 0, stream>>>(
        q1, k1, v1, o1, nw1, q2, k2, v2, o2, nw2, nblk1);
}